// Round 8
// baseline (514.652 us; speedup 1.0000x reference)
//
#include <hip/hip_runtime.h>
#include <math.h>

#define NSWEEP 7
#define NCHUNK 16   // n-chunks in max_outer (2048/16 = 128 rows per block)
#define NB 2        // batches per jacobi block (ILP packing)

__device__ __forceinline__ float dot4f(const float4 a, const float4 b) {
    return a.x * b.x + a.y * b.y + a.z * b.z + a.w * b.w;
}
// monotone float<->uint map so unsigned atomicMax == float max (handles negatives)
__device__ __forceinline__ unsigned mapf(float v) {
    unsigned u = __float_as_uint(v);
    return (u & 0x80000000u) ? ~u : (u | 0x80000000u);
}
__device__ __forceinline__ float unmapf(unsigned u) {
    return __uint_as_float((u & 0x80000000u) ? (u ^ 0x80000000u) : ~u);
}
__device__ __forceinline__ float bperm(int byteaddr, float v) {
    return __int_as_float(__builtin_amdgcn_ds_bpermute(byteaddr, __float_as_int(v)));
}

// ws[0..65535] <- map(-inf)   (atomic-fallback path only)
__global__ __launch_bounds__(256) void init_ws(unsigned* __restrict__ wsu) {
    wsu[blockIdx.x * 256 + threadIdx.x] = 0x007FFFFFu;  // map of 0xFF800000 (-inf)
}

// Shared compute core for both max_outer variants: per-block 4x4-tile max.
__device__ __forceinline__ void max_outer_core(const float* __restrict__ x,
                                               float m[4][4], float* xs,
                                               int b, int n0, int t, int ti, int tj) {
#pragma unroll
    for (int a = 0; a < 4; ++a)
#pragma unroll
        for (int c = 0; c < 4; ++c) m[a][c] = -3.402823466e38f;

    const int row = t >> 3, col8 = t & 7;     // staging map: 32 rows x 8 float-octs
    for (int sub = 0; sub < (2048 / NCHUNK) / 32; ++sub) {
        const float4* src4 =
            (const float4*)(x + (size_t)(b * 2048 + n0 + sub * 32 + row) * 64) + col8 * 2;
        float4* dst4 = (float4*)(xs + row * 64) + col8 * 2;
        dst4[0] = src4[0];
        dst4[1] = src4[1];
        __syncthreads();
#pragma unroll 8
        for (int rr = 0; rr < 32; ++rr) {
            const float4 av = ((const float4*)(xs + rr * 64))[ti];  // broadcast read
            const float4 bv = ((const float4*)(xs + rr * 64))[tj];  // stride-1 read
            const float aa[4] = {av.x, av.y, av.z, av.w};
            const float bb[4] = {bv.x, bv.y, bv.z, bv.w};
#pragma unroll
            for (int a = 0; a < 4; ++a)
#pragma unroll
                for (int c = 0; c < 4; ++c) m[a][c] = fmaxf(m[a][c], aa[a] * bb[c]);
        }
        __syncthreads();
    }
}

// No-atomic path: each (chunk,b) block writes its private 64x64 max partial.
// ws layout: wsp[(b*NCHUNK + chunk)*4096 + i*64 + j]. grid = (NCHUNK, 16).
__global__ __launch_bounds__(256) void max_outer_part(const float* __restrict__ x,
                                                      float* __restrict__ wsp) {
    __shared__ __align__(16) float xs[32 * 64];
    const int b = blockIdx.y;
    const int t = threadIdx.x;
    const int ti = t >> 4, tj = t & 15;
    float m[4][4];
    max_outer_core(x, m, xs, b, blockIdx.x * (2048 / NCHUNK), t, ti, tj);
    float* cell = wsp + (((size_t)b * NCHUNK + blockIdx.x) << 12);
#pragma unroll
    for (int a = 0; a < 4; ++a) {
        float4 v;
        v.x = m[a][0]; v.y = m[a][1]; v.z = m[a][2]; v.w = m[a][3];
        *(float4*)(cell + (ti * 4 + a) * 64 + tj * 4) = v;
    }
}

// Atomic fallback (used only if ws too small): upper triangle only.
__global__ __launch_bounds__(256) void max_outer_atomic(const float* __restrict__ x,
                                                        unsigned* __restrict__ wsu) {
    __shared__ __align__(16) float xs[32 * 64];
    const int b = blockIdx.y;
    const int t = threadIdx.x;
    const int ti = t >> 4, tj = t & 15;
    float m[4][4];
    max_outer_core(x, m, xs, b, blockIdx.x * (2048 / NCHUNK), t, ti, tj);
    unsigned* cell = wsu + b * 4096;
#pragma unroll
    for (int a = 0; a < 4; ++a)
#pragma unroll
        for (int c = 0; c < 4; ++c) {
            const int gi = ti * 4 + a, gj = tj * 4 + c;
            if (gj >= gi) atomicMax(cell + gi * 64 + gj, mapf(m[a][c]));
        }
}

__device__ __forceinline__ float dot32(const float* w, const float* p) {
    float g0 = 0, g1 = 0, g2 = 0, g3 = 0;
#pragma unroll
    for (int i = 0; i < 32; i += 4) {
        g0 = fmaf(w[i + 0], p[i + 0], g0);
        g1 = fmaf(w[i + 1], p[i + 1], g1);
        g2 = fmaf(w[i + 2], p[i + 2], g2);
        g3 = fmaf(w[i + 3], p[i + 3], g3);
    }
    return (g0 + g1) + (g2 + g3);
}

__device__ __forceinline__ void rot_update(float g, float np, bool lo, float& n,
                                           float* w, const float* p) {
    float cc = 1.f, ss2 = 0.f, dn = 0.f;
    if (fabsf(g) > 1e-25f) {
        const float a2 = lo ? n : np;   // norm^2 of lower-indexed column
        const float b2 = lo ? np : n;
        const float tau = (b2 - a2) * 0.5f * __builtin_amdgcn_rcpf(g);
        const float t = (tau >= 0.f ? 1.f : -1.f) *
                        __builtin_amdgcn_rcpf(fabsf(tau) + sqrtf(fmaf(tau, tau, 1.f)));
        cc = __builtin_amdgcn_rsqf(fmaf(t, t, 1.f));
        const float s = t * cc;
        const float sg = lo ? -1.f : 1.f;
        ss2 = sg * s;          // lo: w' = c w - s p ; hi: w' = c w + s p
        dn = sg * (t * g);     // a2' = a2 - t g ; b2' = b2 + t g
    }
    n += dn;
#pragma unroll
    for (int i = 0; i < 32; ++i) w[i] = fmaf(ss2, p[i], cc * w[i]);
}

// One-sided Jacobi, 2 waves per batch-pair, NB=2 batches packed per wave for ILP.
// Wave W owns COLUMNS W*32..W*32+31 of both batches; each column split across
// lanes l / l+32 (row halves). Rounds m=1..31: intra-wave (bpermute+shfl, no
// barrier). Rounds m=32..63: cross-wave via double-buffered LDS (1 barrier).
// The two batches' chains are independent -> compiler interleaves, filling
// latency stalls. grid = 8, block = 128.
__global__ __launch_bounds__(128, 1) void jacobi_sqrt(const void* __restrict__ wsv,
                                                      float* __restrict__ out,
                                                      int nchunk, int mapped) {
    __shared__ __align__(16) float Mlds[NB][64 * 68];      // original M rows
    __shared__ __align__(16) float Ulds[NB][64 * 68];      // U rows
    __shared__ __align__(16) float gl[NB][64];             // signed sqrt eigenvalues
    __shared__ __align__(16) float xbuf[2][NB][2][64][36]; // [buf][bi][wave][lane][.]
    __shared__ float gred[2][NB][2][64];                   // reductions
    const int bp = blockIdx.x;                // batch pair: batches bp and bp+8
    const int tid = threadIdx.x;
    const int wave = tid >> 6;
    const int lane = tid & 63;
    const int col = wave * 32 + (lane & 31);  // column this lane serves
    const int r0 = (lane >> 5) * 32;          // first row of the half it holds

    float w[NB][32], p[NB][32], n[NB];
    // ---- load half-columns of both batches + stash M rows in LDS ----
    if (mapped) {
        const unsigned* wsu = (const unsigned*)wsv;
#pragma unroll
        for (int bi = 0; bi < NB; ++bi) {
            const int b = bp + bi * 8;
#pragma unroll
            for (int i = 0; i < 32; ++i) {
                const int row = r0 + i;
                const int rr = row < col ? row : col;
                const int cc = row < col ? col : row;
                const float v = unmapf(wsu[b * 4096 + rr * 64 + cc]);
                w[bi][i] = v;
                Mlds[bi][row * 68 + col] = v;
            }
        }
    } else {
#pragma unroll
        for (int bi = 0; bi < NB; ++bi)
#pragma unroll
            for (int i = 0; i < 32; ++i) w[bi][i] = -3.402823466e38f;
#pragma unroll 1
        for (int ch = 0; ch < nchunk; ++ch) {
#pragma unroll
            for (int bi = 0; bi < NB; ++bi) {
                const float* base = (const float*)wsv +
                    (((size_t)(bp + bi * 8) * nchunk + ch) << 12) + (size_t)r0 * 64 + col;
#pragma unroll
                for (int i = 0; i < 32; ++i) w[bi][i] = fmaxf(w[bi][i], base[i * 64]);
            }
        }
#pragma unroll
        for (int bi = 0; bi < NB; ++bi)
#pragma unroll
            for (int i = 0; i < 32; ++i) Mlds[bi][(r0 + i) * 68 + col] = w[bi][i];
    }
    // initial column norms (maintained analytically through the rotations)
#pragma unroll
    for (int bi = 0; bi < NB; ++bi) {
        const float part = dot32(w[bi], w[bi]);
        n[bi] = part + __shfl_xor(part, 32);
    }

#pragma unroll 1
    for (int sweep = 0; sweep < NSWEEP; ++sweep) {
        // ---- intra-wave rounds: no barrier ----
#pragma unroll 1
        for (int m = 1; m < 32; ++m) {
            const int paddr = (lane ^ m) << 2;
            const float np0 = bperm(paddr, n[0]);
            const float np1 = bperm(paddr, n[1]);
#pragma unroll
            for (int i = 0; i < 32; ++i) p[0][i] = bperm(paddr, w[0][i]);
#pragma unroll
            for (int i = 0; i < 32; ++i) p[1][i] = bperm(paddr, w[1][i]);
            const float part0 = dot32(w[0], p[0]);
            const float part1 = dot32(w[1], p[1]);
            const float g0 = part0 + __shfl_xor(part0, 32);
            const float g1 = part1 + __shfl_xor(part1, 32);
            const bool lo = (lane & 31) < ((lane & 31) ^ m);
            rot_update(g0, np0, lo, n[0], w[0], p[0]);
            rot_update(g1, np1, lo, n[1], w[1], p[1]);
        }
        // ---- cross-wave rounds: one barrier each (double-buffered exchange) ----
#pragma unroll 1
        for (int m = 32; m < 64; ++m) {
#pragma unroll
            for (int bi = 0; bi < NB; ++bi) {
                float* myx = &xbuf[m & 1][bi][wave][lane][0];
#pragma unroll
                for (int c = 0; c < 8; ++c) {
                    float4 v;
                    v.x = w[bi][4 * c + 0]; v.y = w[bi][4 * c + 1];
                    v.z = w[bi][4 * c + 2]; v.w = w[bi][4 * c + 3];
                    ((float4*)myx)[c] = v;
                }
                myx[32] = n[bi];
            }
            __syncthreads();
            float np[NB];
#pragma unroll
            for (int bi = 0; bi < NB; ++bi) {
                const float* ox = &xbuf[m & 1][bi][wave ^ 1][lane ^ (m & 31)][0];
#pragma unroll
                for (int c = 0; c < 8; ++c) {
                    const float4 v = ((const float4*)ox)[c];
                    p[bi][4 * c + 0] = v.x; p[bi][4 * c + 1] = v.y;
                    p[bi][4 * c + 2] = v.z; p[bi][4 * c + 3] = v.w;
                }
                np[bi] = ox[32];
            }
            const float part0 = dot32(w[0], p[0]);
            const float part1 = dot32(w[1], p[1]);
            const float g0 = part0 + __shfl_xor(part0, 32);
            const float g1 = part1 + __shfl_xor(part1, 32);
            const bool lo = (wave == 0);  // wave-0 columns have the lower index
            rot_update(g0, np[0], lo, n[0], w[0], p[0]);
            rot_update(g1, np[1], lo, n[1], w[1], p[1]);
        }
    }

    // ---- exact norm -> u; U rows into LDS ----
#pragma unroll
    for (int bi = 0; bi < NB; ++bi) {
        const float part = dot32(w[bi], w[bi]);
        const float nrm = part + __shfl_xor(part, 32);
        const float inv = rsqrtf(fmaxf(nrm, 1e-30f));
#pragma unroll
        for (int i = 0; i < 32; ++i) w[bi][i] *= inv;
#pragma unroll
        for (int i = 0; i < 32; ++i) Ulds[bi][(r0 + i) * 68 + col] = w[bi][i];
    }
    __syncthreads();

    // ---- epilogue per batch (row-split layout: lane = column, wave owns rows) ----
    const int rbase = wave * 32;
    const int obase = 32 - rbase;
#pragma unroll 1
    for (int bi = 0; bi < NB; ++bi) {
        const int b = bp + bi * 8;
        float w2[32], p2[32];
#pragma unroll
        for (int i = 0; i < 32; ++i) w2[i] = Ulds[bi][(rbase + i) * 68 + lane];
#pragma unroll
        for (int i = 0; i < 32; ++i) p2[i] = Ulds[bi][(obase + i) * 68 + lane];

        // signed eigenvalue: rho = u^T M u
        {
            float rho = 0.f;
#pragma unroll 1
            for (int ii = 0; ii < 32; ++ii) {
                const int i = rbase + ii;
                const float4* mrw = (const float4*)(Mlds[bi] + i * 68) + (rbase >> 2);
                const float4* mrp = (const float4*)(Mlds[bi] + i * 68) + (obase >> 2);
                float z0 = 0, z1 = 0, z2 = 0, z3 = 0;
#pragma unroll
                for (int c = 0; c < 8; c += 4) {
                    float4 mv;
                    mv = mrw[c + 0]; z0 += mv.x * w2[4 * c + 0]  + mv.y * w2[4 * c + 1]  + mv.z * w2[4 * c + 2]  + mv.w * w2[4 * c + 3];
                    mv = mrw[c + 1]; z1 += mv.x * w2[4 * c + 4]  + mv.y * w2[4 * c + 5]  + mv.z * w2[4 * c + 6]  + mv.w * w2[4 * c + 7];
                    mv = mrw[c + 2]; z2 += mv.x * w2[4 * c + 8]  + mv.y * w2[4 * c + 9]  + mv.z * w2[4 * c + 10] + mv.w * w2[4 * c + 11];
                    mv = mrw[c + 3]; z3 += mv.x * w2[4 * c + 12] + mv.y * w2[4 * c + 13] + mv.z * w2[4 * c + 14] + mv.w * w2[4 * c + 15];
                    mv = mrp[c + 0]; z0 += mv.x * p2[4 * c + 0]  + mv.y * p2[4 * c + 1]  + mv.z * p2[4 * c + 2]  + mv.w * p2[4 * c + 3];
                    mv = mrp[c + 1]; z1 += mv.x * p2[4 * c + 4]  + mv.y * p2[4 * c + 5]  + mv.z * p2[4 * c + 6]  + mv.w * p2[4 * c + 7];
                    mv = mrp[c + 2]; z2 += mv.x * p2[4 * c + 8]  + mv.y * p2[4 * c + 9]  + mv.z * p2[4 * c + 10] + mv.w * p2[4 * c + 11];
                    mv = mrp[c + 3]; z3 += mv.x * p2[4 * c + 12] + mv.y * p2[4 * c + 13] + mv.z * p2[4 * c + 14] + mv.w * p2[4 * c + 15];
                }
                rho = fmaf(w2[ii], (z0 + z1) + (z2 + z3), rho);
            }
            gred[1][bi][wave][lane] = rho;
            __syncthreads();
            const float rs = gred[1][bi][0][lane] + gred[1][bi][1][lane];
            gl[bi][lane] = (rs >= 0.f) ? sqrtf(rs) : -sqrtf(-rs);
        }
        __syncthreads();

        // F[i][lane] = sum_k g_k U[i][k] U[lane][k], i over my rows
        {
            float4 rr[16];  // row `lane` of U scaled by g
#pragma unroll
            for (int c = 0; c < 16; ++c) {
                const float4 uv = ((const float4*)(Ulds[bi] + lane * 68))[c];
                const float4 gv = ((const float4*)gl[bi])[c];  // broadcast
                rr[c].x = uv.x * gv.x; rr[c].y = uv.y * gv.y;
                rr[c].z = uv.z * gv.z; rr[c].w = uv.w * gv.w;
            }
            float sq = 0.f;
#pragma unroll 1
            for (int ii = 0; ii < 32; ++ii) {
                const int i = rbase + ii;
                const float4* ur = (const float4*)(Ulds[bi] + i * 68);  // broadcast
                float f0 = 0, f1 = 0, f2 = 0, f3 = 0;
#pragma unroll
                for (int c = 0; c < 16; c += 4) {
                    f0 += dot4f(ur[c + 0], rr[c + 0]);
                    f1 += dot4f(ur[c + 1], rr[c + 1]);
                    f2 += dot4f(ur[c + 2], rr[c + 2]);
                    f3 += dot4f(ur[c + 3], rr[c + 3]);
                }
                const float fv = (f0 + f1) + (f2 + f3);
                sq = fmaf(fv, fv, sq);
                Mlds[bi][i * 68 + lane] = fv;  // M is dead; reuse as F staging
            }
#pragma unroll
            for (int d = 1; d < 64; d <<= 1) sq += __shfl_xor(sq, d);
            gred[0][bi][wave][lane] = sq;
            __syncthreads();
            const float tot = gred[0][bi][0][lane] + gred[0][bi][1][lane];
            const float scale = 1.f / fmaxf(sqrtf(tot), 1e-12f);
#pragma unroll 1
            for (int ii = 0; ii < 32; ++ii)
                out[(size_t)b * 4096 + (rbase + ii) * 64 + lane] =
                    Mlds[bi][(rbase + ii) * 68 + lane] * scale;
        }
    }
}

extern "C" void kernel_launch(void* const* d_in, const int* in_sizes, int n_in,
                              void* d_out, int out_size, void* d_ws, size_t ws_size,
                              hipStream_t stream) {
    const float* x = (const float*)d_in[0];   // [16,1,2048,64] fp32
    float* out = (float*)d_out;               // [16,4096] fp32

    const size_t need = (size_t)NCHUNK * 16 * 4096 * sizeof(float);  // 4 MB
    if (ws_size >= need) {
        // no-atomic path: partial max blocks in ws, reduced in jacobi prologue
        float* wsp = (float*)d_ws;
        hipLaunchKernelGGL(max_outer_part, dim3(NCHUNK, 16), dim3(256), 0, stream, x, wsp);
        hipLaunchKernelGGL(jacobi_sqrt, dim3(8), dim3(128), 0, stream,
                           (const void*)wsp, out, NCHUNK, 0);
    } else {
        // fallback: atomic max into mapped uints
        unsigned* wsu = (unsigned*)d_ws;
        hipLaunchKernelGGL(init_ws, dim3(256), dim3(256), 0, stream, wsu);
        hipLaunchKernelGGL(max_outer_atomic, dim3(NCHUNK, 16), dim3(256), 0, stream, x, wsu);
        hipLaunchKernelGGL(jacobi_sqrt, dim3(8), dim3(128), 0, stream,
                           (const void*)wsu, out, 1, 1);
    }
}

// Round 10
// 342.916 us; speedup vs baseline: 1.5008x; 1.5008x over previous
//
#include <hip/hip_runtime.h>
#include <math.h>

#define NSWEEP 7
#define NCHUNK 16   // n-chunks in max_outer (2048/16 = 128 rows per block)

__device__ __forceinline__ float dot4f(const float4 a, const float4 b) {
    return a.x * b.x + a.y * b.y + a.z * b.z + a.w * b.w;
}
// monotone float<->uint map so unsigned atomicMax == float max (handles negatives)
__device__ __forceinline__ unsigned mapf(float v) {
    unsigned u = __float_as_uint(v);
    return (u & 0x80000000u) ? ~u : (u | 0x80000000u);
}
__device__ __forceinline__ float unmapf(unsigned u) {
    return __uint_as_float((u & 0x80000000u) ? (u ^ 0x80000000u) : ~u);
}

// ws[0..65535] <- map(-inf)   (atomic-fallback path only)
__global__ __launch_bounds__(256) void init_ws(unsigned* __restrict__ wsu) {
    wsu[blockIdx.x * 256 + threadIdx.x] = 0x007FFFFFu;  // map of 0xFF800000 (-inf)
}

// Shared compute core for both max_outer variants: per-block 4x4-tile max.
__device__ __forceinline__ void max_outer_core(const float* __restrict__ x,
                                               float m[4][4], float* xs,
                                               int b, int n0, int t, int ti, int tj) {
#pragma unroll
    for (int a = 0; a < 4; ++a)
#pragma unroll
        for (int c = 0; c < 4; ++c) m[a][c] = -3.402823466e38f;

    const int row = t >> 3, col8 = t & 7;     // staging map: 32 rows x 8 float-octs
    for (int sub = 0; sub < (2048 / NCHUNK) / 32; ++sub) {
        const float4* src4 =
            (const float4*)(x + (size_t)(b * 2048 + n0 + sub * 32 + row) * 64) + col8 * 2;
        float4* dst4 = (float4*)(xs + row * 64) + col8 * 2;
        dst4[0] = src4[0];
        dst4[1] = src4[1];
        __syncthreads();
#pragma unroll 8
        for (int rr = 0; rr < 32; ++rr) {
            const float4 av = ((const float4*)(xs + rr * 64))[ti];  // broadcast read
            const float4 bv = ((const float4*)(xs + rr * 64))[tj];  // stride-1 read
            const float aa[4] = {av.x, av.y, av.z, av.w};
            const float bb[4] = {bv.x, bv.y, bv.z, bv.w};
#pragma unroll
            for (int a = 0; a < 4; ++a)
#pragma unroll
                for (int c = 0; c < 4; ++c) m[a][c] = fmaxf(m[a][c], aa[a] * bb[c]);
        }
        __syncthreads();
    }
}

// No-atomic path: each (chunk,b) block writes its private 64x64 max partial.
// ws layout: wsp[(b*NCHUNK + chunk)*4096 + i*64 + j]. grid = (NCHUNK, 16).
__global__ __launch_bounds__(256) void max_outer_part(const float* __restrict__ x,
                                                      float* __restrict__ wsp) {
    __shared__ __align__(16) float xs[32 * 64];
    const int b = blockIdx.y;
    const int t = threadIdx.x;
    const int ti = t >> 4, tj = t & 15;
    float m[4][4];
    max_outer_core(x, m, xs, b, blockIdx.x * (2048 / NCHUNK), t, ti, tj);
    float* cell = wsp + (((size_t)b * NCHUNK + blockIdx.x) << 12);
#pragma unroll
    for (int a = 0; a < 4; ++a) {
        float4 v;
        v.x = m[a][0]; v.y = m[a][1]; v.z = m[a][2]; v.w = m[a][3];
        *(float4*)(cell + (ti * 4 + a) * 64 + tj * 4) = v;
    }
}

// Atomic fallback (used only if ws too small): upper triangle only.
__global__ __launch_bounds__(256) void max_outer_atomic(const float* __restrict__ x,
                                                        unsigned* __restrict__ wsu) {
    __shared__ __align__(16) float xs[32 * 64];
    const int b = blockIdx.y;
    const int t = threadIdx.x;
    const int ti = t >> 4, tj = t & 15;
    float m[4][4];
    max_outer_core(x, m, xs, b, blockIdx.x * (2048 / NCHUNK), t, ti, tj);
    unsigned* cell = wsu + b * 4096;
#pragma unroll
    for (int a = 0; a < 4; ++a)
#pragma unroll
        for (int c = 0; c < 4; ++c) {
            const int gi = ti * 4 + a, gj = tj * 4 + c;
            if (gj >= gi) atomicMax(cell + gi * 64 + gj, mapf(m[a][c]));
        }
}

__device__ __forceinline__ float dot32(const float* w, const float* p) {
    float g0 = 0, g1 = 0, g2 = 0, g3 = 0;
#pragma unroll
    for (int i = 0; i < 32; i += 4) {
        g0 = fmaf(w[i + 0], p[i + 0], g0);
        g1 = fmaf(w[i + 1], p[i + 1], g1);
        g2 = fmaf(w[i + 2], p[i + 2], g2);
        g3 = fmaf(w[i + 3], p[i + 3], g3);
    }
    return (g0 + g1) + (g2 + g3);
}

__device__ __forceinline__ void rot_update(float g, float np, bool lo, float& n,
                                           float* w, const float* p) {
    float cc = 1.f, ss2 = 0.f, dn = 0.f;
    if (fabsf(g) > 1e-25f) {
        const float a2 = lo ? n : np;   // norm^2 of lower-indexed column
        const float b2 = lo ? np : n;
        const float tau = (b2 - a2) * 0.5f * __builtin_amdgcn_rcpf(g);
        const float t = (tau >= 0.f ? 1.f : -1.f) *
                        __builtin_amdgcn_rcpf(fabsf(tau) + sqrtf(fmaf(tau, tau, 1.f)));
        cc = __builtin_amdgcn_rsqf(fmaf(t, t, 1.f));
        const float s = t * cc;
        const float sg = lo ? -1.f : 1.f;
        ss2 = sg * s;          // lo: w' = c w - s p ; hi: w' = c w + s p
        dn = sg * (t * g);     // a2' = a2 - t g ; b2' = b2 + t g
    }
    n += dn;
#pragma unroll
    for (int i = 0; i < 32; ++i) w[i] = fmaf(ss2, p[i], cc * w[i]);
}

// One-sided Jacobi, 2 waves per batch (R7-proven schedule).
// Wave W owns COLUMNS W*32..W*32+31; each column split across lanes l / l+32.
// Rounds m=1..31: intra-wave. Partner half-column via single-buffer LDS
//   exchange (8x ds_write_b128 + 8x ds_read_b128, stride-36 padded). No
//   __syncthreads needed: the DS pipe executes a wave's LDS ops in order, so
//   every lane's writes retire before the read instruction executes. BUT the
//   compiler can prove lane != lane^m and would reorder the loads above the
//   stores -- an explicit compiler-only memory fence (zero instructions)
//   pins the order.
// Rounds m=32..63: cross-wave via double-buffered LDS exchange (1 barrier).
// grid = 16, block = 128. mapped=1: ws holds atomic-mapped uints (nchunk=1);
// mapped=0: ws holds nchunk plain-float partial blocks to max-reduce.
__global__ __launch_bounds__(128) void jacobi_sqrt(const void* __restrict__ wsv,
                                                   float* __restrict__ out,
                                                   int nchunk, int mapped) {
    __shared__ __align__(16) float Mlds[64 * 68];      // original M rows (stride 68)
    __shared__ __align__(16) float Ulds[64 * 68];      // U rows
    __shared__ __align__(16) float gl[64];             // signed sqrt eigenvalues
    __shared__ __align__(16) float xbuf[2][2][64][36]; // [buf][wave][lane][32w+n+pad]
    __shared__ float gred[2][2][64];                   // epilogue reductions
    const int b = blockIdx.x;
    const int tid = threadIdx.x;
    const int wave = tid >> 6;
    const int lane = tid & 63;
    const int col = wave * 32 + (lane & 31);  // column this lane serves
    const int r0 = (lane >> 5) * 32;          // first row of the half it holds

    float w[32], p[32];
    // load my half-column + stash M rows in LDS for the epilogue
    if (mapped) {
        const unsigned* wsu = (const unsigned*)wsv;
#pragma unroll
        for (int i = 0; i < 32; ++i) {
            const int row = r0 + i;
            const int rr = row < col ? row : col;
            const int cc = row < col ? col : row;
            const float v = unmapf(wsu[b * 4096 + rr * 64 + cc]);
            w[i] = v;
            Mlds[row * 68 + col] = v;
        }
    } else {
        const float* wsp = (const float*)wsv + (((size_t)b * nchunk) << 12);
#pragma unroll
        for (int i = 0; i < 32; ++i) w[i] = -3.402823466e38f;
#pragma unroll 1
        for (int ch = 0; ch < nchunk; ++ch) {
            const float* base = wsp + ((size_t)ch << 12) + (size_t)r0 * 64 + col;
#pragma unroll
            for (int i = 0; i < 32; ++i) w[i] = fmaxf(w[i], base[i * 64]);
        }
#pragma unroll
        for (int i = 0; i < 32; ++i) Mlds[(r0 + i) * 68 + col] = w[i];
    }
    // initial column norm^2 (maintained analytically through the rotations)
    float n;
    {
        const float part = dot32(w, w);
        n = part + __shfl_xor(part, 32);
    }

#pragma unroll 1
    for (int sweep = 0; sweep < NSWEEP; ++sweep) {
        // ---- intra-wave rounds: single-buffer LDS exchange, no barrier ----
#pragma unroll 1
        for (int m = 1; m < 32; ++m) {
            float* myx = &xbuf[0][wave][lane][0];
#pragma unroll
            for (int c = 0; c < 8; ++c) {
                float4 v;
                v.x = w[4 * c + 0]; v.y = w[4 * c + 1];
                v.z = w[4 * c + 2]; v.w = w[4 * c + 3];
                ((float4*)myx)[c] = v;
            }
            myx[32] = n;
            // compiler-only fence: forbids hoisting the (provably non-aliasing
            // from a single thread's view) loads above the stores. HW order is
            // guaranteed by the in-order per-wave DS pipe.
            asm volatile("" ::: "memory");
            const float* ox = &xbuf[0][wave][lane ^ m][0];
#pragma unroll
            for (int c = 0; c < 8; ++c) {
                const float4 v = ((const float4*)ox)[c];
                p[4 * c + 0] = v.x; p[4 * c + 1] = v.y;
                p[4 * c + 2] = v.z; p[4 * c + 3] = v.w;
            }
            const float np = ox[32];
            const float part = dot32(w, p);
            const float g = part + __shfl_xor(part, 32);
            const bool lo = (lane & 31) < ((lane & 31) ^ m);
            rot_update(g, np, lo, n, w, p);
        }
        // ---- cross-wave rounds: one barrier each (double-buffered exchange) ----
#pragma unroll 1
        for (int m = 32; m < 64; ++m) {
            float* myx = &xbuf[m & 1][wave][lane][0];
#pragma unroll
            for (int c = 0; c < 8; ++c) {
                float4 v;
                v.x = w[4 * c + 0]; v.y = w[4 * c + 1];
                v.z = w[4 * c + 2]; v.w = w[4 * c + 3];
                ((float4*)myx)[c] = v;
            }
            myx[32] = n;
            __syncthreads();
            const float* ox = &xbuf[m & 1][wave ^ 1][lane ^ (m & 31)][0];
#pragma unroll
            for (int c = 0; c < 8; ++c) {
                const float4 v = ((const float4*)ox)[c];
                p[4 * c + 0] = v.x; p[4 * c + 1] = v.y;
                p[4 * c + 2] = v.z; p[4 * c + 3] = v.w;
            }
            const float np = ox[32];
            const float part = dot32(w, p);
            const float g = part + __shfl_xor(part, 32);
            const bool lo = (wave == 0);  // wave-0 columns have the lower index
            rot_update(g, np, lo, n, w, p);
        }
    }

    // ---- exact norm -> u (intra-wave) ----
    {
        const float part = dot32(w, w);
        const float nrm = part + __shfl_xor(part, 32);
        const float inv = rsqrtf(fmaxf(nrm, 1e-30f));
#pragma unroll
        for (int i = 0; i < 32; ++i) w[i] *= inv;
    }
    // U rows into LDS (conflict-free: distinct cols mod 32 per half)
#pragma unroll
    for (int i = 0; i < 32; ++i) Ulds[(r0 + i) * 68 + col] = w[i];
    __syncthreads();

    // ---- switch to row-split layout: lane = column, wave owns rows ----
    const int rbase = wave * 32;
    const int obase = 32 - rbase;
    float w2[32], p2[32];
#pragma unroll
    for (int i = 0; i < 32; ++i) w2[i] = Ulds[(rbase + i) * 68 + lane];
#pragma unroll
    for (int i = 0; i < 32; ++i) p2[i] = Ulds[(obase + i) * 68 + lane];

    // ---- signed eigenvalue: rho = u^T M u (i split by ownership, j full) ----
    {
        float rho = 0.f;
#pragma unroll 1
        for (int ii = 0; ii < 32; ++ii) {
            const int i = rbase + ii;
            const float4* mrw = (const float4*)(Mlds + i * 68) + (rbase >> 2);  // rows of w2
            const float4* mrp = (const float4*)(Mlds + i * 68) + (obase >> 2);  // rows of p2
            float z0 = 0, z1 = 0, z2 = 0, z3 = 0;
#pragma unroll
            for (int c = 0; c < 8; c += 4) {
                float4 mv;
                mv = mrw[c + 0]; z0 += mv.x * w2[4 * c + 0]  + mv.y * w2[4 * c + 1]  + mv.z * w2[4 * c + 2]  + mv.w * w2[4 * c + 3];
                mv = mrw[c + 1]; z1 += mv.x * w2[4 * c + 4]  + mv.y * w2[4 * c + 5]  + mv.z * w2[4 * c + 6]  + mv.w * w2[4 * c + 7];
                mv = mrw[c + 2]; z2 += mv.x * w2[4 * c + 8]  + mv.y * w2[4 * c + 9]  + mv.z * w2[4 * c + 10] + mv.w * w2[4 * c + 11];
                mv = mrw[c + 3]; z3 += mv.x * w2[4 * c + 12] + mv.y * w2[4 * c + 13] + mv.z * w2[4 * c + 14] + mv.w * w2[4 * c + 15];
                mv = mrp[c + 0]; z0 += mv.x * p2[4 * c + 0]  + mv.y * p2[4 * c + 1]  + mv.z * p2[4 * c + 2]  + mv.w * p2[4 * c + 3];
                mv = mrp[c + 1]; z1 += mv.x * p2[4 * c + 4]  + mv.y * p2[4 * c + 5]  + mv.z * p2[4 * c + 6]  + mv.w * p2[4 * c + 7];
                mv = mrp[c + 2]; z2 += mv.x * p2[4 * c + 8]  + mv.y * p2[4 * c + 9]  + mv.z * p2[4 * c + 10] + mv.w * p2[4 * c + 11];
                mv = mrp[c + 3]; z3 += mv.x * p2[4 * c + 12] + mv.y * p2[4 * c + 13] + mv.z * p2[4 * c + 14] + mv.w * p2[4 * c + 15];
            }
            rho = fmaf(w2[ii], (z0 + z1) + (z2 + z3), rho);
        }
        gred[1][wave][lane] = rho;
        __syncthreads();
        const float rs = gred[1][0][lane] + gred[1][1][lane];
        gl[lane] = (rs >= 0.f) ? sqrtf(rs) : -sqrtf(-rs);  // both waves write same value
    }
    __syncthreads();

    // ---- F[i][lane] = sum_k g_k U[i][k] U[lane][k], i over my rows ----
    {
        float4 rr[16];  // row `lane` of U scaled by g
#pragma unroll
        for (int c = 0; c < 16; ++c) {
            const float4 uv = ((const float4*)(Ulds + lane * 68))[c];
            const float4 gv = ((const float4*)gl)[c];  // broadcast
            rr[c].x = uv.x * gv.x; rr[c].y = uv.y * gv.y;
            rr[c].z = uv.z * gv.z; rr[c].w = uv.w * gv.w;
        }
        float sq = 0.f;
#pragma unroll 1
        for (int ii = 0; ii < 32; ++ii) {
            const int i = rbase + ii;
            const float4* ur = (const float4*)(Ulds + i * 68);  // broadcast
            float f0 = 0, f1 = 0, f2 = 0, f3 = 0;
#pragma unroll
            for (int c = 0; c < 16; c += 4) {
                f0 += dot4f(ur[c + 0], rr[c + 0]);
                f1 += dot4f(ur[c + 1], rr[c + 1]);
                f2 += dot4f(ur[c + 2], rr[c + 2]);
                f3 += dot4f(ur[c + 3], rr[c + 3]);
            }
            const float fv = (f0 + f1) + (f2 + f3);
            sq = fmaf(fv, fv, sq);
            Mlds[i * 68 + lane] = fv;  // M is dead; reuse as F staging
        }
#pragma unroll
        for (int d = 1; d < 64; d <<= 1) sq += __shfl_xor(sq, d);
        gred[0][wave][lane] = sq;
        __syncthreads();
        const float tot = gred[0][0][lane] + gred[0][1][lane];
        const float scale = 1.f / fmaxf(sqrtf(tot), 1e-12f);
#pragma unroll 1
        for (int ii = 0; ii < 32; ++ii)
            out[(size_t)b * 4096 + (rbase + ii) * 64 + lane] =
                Mlds[(rbase + ii) * 68 + lane] * scale;
    }
}

extern "C" void kernel_launch(void* const* d_in, const int* in_sizes, int n_in,
                              void* d_out, int out_size, void* d_ws, size_t ws_size,
                              hipStream_t stream) {
    const float* x = (const float*)d_in[0];   // [16,1,2048,64] fp32
    float* out = (float*)d_out;               // [16,4096] fp32

    const size_t need = (size_t)NCHUNK * 16 * 4096 * sizeof(float);  // 4 MB
    if (ws_size >= need) {
        // no-atomic path: partial max blocks in ws, reduced in jacobi prologue
        float* wsp = (float*)d_ws;
        hipLaunchKernelGGL(max_outer_part, dim3(NCHUNK, 16), dim3(256), 0, stream, x, wsp);
        hipLaunchKernelGGL(jacobi_sqrt, dim3(16), dim3(128), 0, stream,
                           (const void*)wsp, out, NCHUNK, 0);
    } else {
        // fallback: atomic max into mapped uints
        unsigned* wsu = (unsigned*)d_ws;
        hipLaunchKernelGGL(init_ws, dim3(256), dim3(256), 0, stream, wsu);
        hipLaunchKernelGGL(max_outer_atomic, dim3(NCHUNK, 16), dim3(256), 0, stream, x, wsu);
        hipLaunchKernelGGL(jacobi_sqrt, dim3(16), dim3(128), 0, stream,
                           (const void*)wsu, out, 1, 1);
    }
}